// Round 10
// baseline (31.353 us; speedup 1.0000x reference)
//
#include <hip/hip_runtime.h>

// CWT, truncated direct correlation, REAL PART ONLY (harness validates
// out_size = B*128*N float32 = real part of the complex64 reference).
// u-shifted form: y[n] = sum_{u=1..T} xpad[n+u] * tw[u],
//   xpad[i] = x[i-8192] (zero outside), tw[u] = g(u-1)*cos(2*pi*f*(u-1)),
//   g(t)=exp(-t^2/2sigma^2), sigma=6*scale/2pi, T=ceil(5*sigma)+1 <= 307.
// ch%4 -> x row, ch%32 -> wavelet; 4|32 -> 32 unique channels, 4 copies.
// y==0 for n < 8192-T; T<=307 -> tiles 0..14 (512-wide) zero for ALL scales.
//
// R9 lesson: cutting FMA work 28% gained only 10% -> the constant was the
// stage-into-LDS skeleton (scalar loads -> ds_write -> lgkm -> ds_read), not
// compute. R10: NO LDS AT ALL. Prep kernel builds zero-padded xpad (1 MB) +
// tap table in d_ws; main kernel reads x directly from global (L1/L2-hit,
// 16B-aligned thanks to the u-shift), rolling float4 window, RPT=8,
// A/B 2-deep pipeline, perfectly balanced blocks (wave0=p, wave1=31-p),
// pair index at stride 68 across blocks -> no CU aliasing.

#define NPIX   16384
#define NSCALE 32
#define NCH    4
#define ALPHA  5.0f
#define PI_F   3.14159265358979f

#define TSZ    384        // tap slots per scale (u-indexed, zero-padded)
#define TAPS_F (NSCALE*TSZ)
#define XROW   16768      // padded row: [8192 zeros][x[0..8575]]
#define XOFF   8192
#define UBLK   512        // outputs per unit (64 lanes * RPT 8)
#define WT0    15         // first working tile
#define NWT    17         // working tiles per scale  (15..31)
#define NZT    15         // zero tiles per scale     (0..14)
#define UPP    68         // units per scale-pair = 4 b * 17 tiles
#define NBLOCK (16*UPP)   // 1088 blocks (2 waves each)
#define NZUNIT (NZT*NSCALE*NCH)   // 1920 zero units of 512 floats

__global__ __launch_bounds__(256) void prep_kernel(
    const float* __restrict__ x,
    const float* __restrict__ scales,
    float* __restrict__ ws)
{
    const int idx = blockIdx.x * 256 + threadIdx.x;
    if (blockIdx.x < 262) {                 // xpad: 16*16768/4 = 67072 float4
        float4* xp4 = reinterpret_cast<float4*>(ws + TAPS_F);
        const int row = idx / (XROW / 4);
        const int i   = (idx % (XROW / 4)) * 4;
        float4 v = {0.f, 0.f, 0.f, 0.f};
        if (i >= XOFF)                       // 8192 % 4 == 0: no straddle
            v = *reinterpret_cast<const float4*>(x + (size_t)row * NPIX + (i - XOFF));
        xp4[idx] = v;
    } else {                                 // taps: 32*384 = 12288 floats
        const int t = idx - 262 * 256;
        const int s = t / TSZ, u = t % TSZ;
        const float scale = scales[s];
        const float f     = 1.0f / scale;
        const float sigma = 6.0f * scale / (2.0f * PI_F);
        int T = (int)ceilf(ALPHA * sigma) + 1;
        if (T > 307) T = 307;
        float v = 0.f;
        if (u >= 1 && u <= T) {
            const float tf = (float)(u - 1);
            v = __expf(-tf * tf / (2.f * sigma * sigma)) * __cosf(2.f * PI_F * f * tf);
        }
        ws[t] = v;
    }
}

// one 16-tap group: 128 FMAs, all indices compile-time after unroll
#define FMAG(TT0, TT1, TT2, TT3, E0, E1, E2, E3, E4, E5)                      \
    do {                                                                      \
        const float e[24] = {E0.x,E0.y,E0.z,E0.w, E1.x,E1.y,E1.z,E1.w,        \
                             E2.x,E2.y,E2.z,E2.w, E3.x,E3.y,E3.z,E3.w,        \
                             E4.x,E4.y,E4.z,E4.w, E5.x,E5.y,E5.z,E5.w};       \
        const float tk[16] = {TT0.x,TT0.y,TT0.z,TT0.w, TT1.x,TT1.y,TT1.z,TT1.w,\
                              TT2.x,TT2.y,TT2.z,TT2.w, TT3.x,TT3.y,TT3.z,TT3.w};\
        _Pragma("unroll")                                                     \
        for (int k = 0; k < 16; ++k) {                                        \
            _Pragma("unroll")                                                 \
            for (int j = 0; j < 8; ++j)                                       \
                acc[j] = fmaf(tk[k], e[k + j], acc[j]);                       \
        }                                                                     \
    } while (0)

__global__ __launch_bounds__(128) void cwt_kernel(
    const float* __restrict__ scales,
    const float* __restrict__ ws,
    float* __restrict__ out)
{
    const int lane = threadIdx.x & 63;
    const int wid  = threadIdx.x >> 6;
    const int Bk   = blockIdx.x;
    const int W    = Bk * 2 + wid;              // global wave id, 0..2175

    const size_t cstride = (size_t)NSCALE * NPIX;

    // ---- zero-fill duty: 1920 zero units of 512 floats, 4 copies each ----
    if (W < NZUNIT) {
        const int zb = W / (NZT * NSCALE);
        const int rr = W % (NZT * NSCALE);
        const int zs = rr / NZT;
        const int zt = rr % NZT;
        float* zp = out + ((size_t)zb * (NSCALE * NCH) + zs) * NPIX
                        + zt * UBLK + lane * 8;
        const float4 z = {0.f, 0.f, 0.f, 0.f};
        #pragma unroll
        for (int q = 0; q < 4; ++q) {
            float4* pp = reinterpret_cast<float4*>(zp + (size_t)q * cstride);
            pp[0] = z; pp[1] = z;
        }
    }

    // ---- unit decode: pair p varies at stride 68 across blocks ----
    const int p    = Bk / UPP;                  // scale pair 0..15
    const int rr2  = Bk % UPP;
    const int b    = rr2 / NWT;                 // batch 0..3
    const int tile = WT0 + (rr2 % NWT);         // 15..31
    const int s    = wid ? (NSCALE - 1 - p) : p;

    const int n0 = tile * UBLK;
    const float scale = scales[s];
    const float sigma = 6.f * scale / (2.f * PI_F);
    int T = (int)ceilf(ALPHA * sigma) + 1;
    if (T > 307) T = 307;
    const int nG  = (T + 16) >> 4;              // ceil((T+1)/16)
    const int gNe = nG + (nG & 1);              // even (taps zero-padded)

    // per-lane window base: element idx = (n0 + 8*lane) + u, 16B-aligned
    const float4* xq = reinterpret_cast<const float4*>(
        ws + TAPS_F + (size_t)(b * NCH + (s & 3)) * XROW + n0 + lane * 8);
    const float4* tp4 = reinterpret_cast<const float4*>(ws + s * TSZ);

    float acc[8];
    #pragma unroll
    for (int j = 0; j < 8; ++j) acc[j] = 0.f;

    // ---- prologue: window (6 f4) + taps (4 f4) for group 0 ----
    float4 a0 = xq[0], a1 = xq[1], a2 = xq[2], a3 = xq[3], a4 = xq[4], a5 = xq[5];
    float4 t0 = tp4[0], t1 = tp4[1], t2 = tp4[2], t3 = tp4[3];

    // ---- A/B pipelined loop: loads for next group before current FMAs ----
    for (int g = 0; g < gNe; g += 2) {
        const int jb = (g + 1) * 4;
        const float4 b0 = a4, b1 = a5;
        const float4 b2 = xq[jb + 2], b3 = xq[jb + 3];
        const float4 b4 = xq[jb + 4], b5 = xq[jb + 5];
        const float4 u0 = tp4[jb + 0], u1 = tp4[jb + 1];
        const float4 u2 = tp4[jb + 2], u3 = tp4[jb + 3];

        FMAG(t0, t1, t2, t3, a0, a1, a2, a3, a4, a5);

        const int ja = (g + 2) * 4;             // overrun safe: taps zero-pad,
        a0 = b4; a1 = b5;                       // xpad sized for gNe+1 groups
        a2 = xq[ja + 2]; a3 = xq[ja + 3];
        a4 = xq[ja + 4]; a5 = xq[ja + 5];
        t0 = tp4[ja + 0]; t1 = tp4[ja + 1];
        t2 = tp4[ja + 2]; t3 = tp4[ja + 3];

        FMAG(u0, u1, u2, u3, b0, b1, b2, b3, b4, b5);
    }

    // ---- store 4 channel copies (2KB contiguous per wave per copy) ----
    float* ob = out + ((size_t)b * (NSCALE * NCH) + s) * NPIX + n0 + lane * 8;
    const float4 v0 = {acc[0], acc[1], acc[2], acc[3]};
    const float4 v1 = {acc[4], acc[5], acc[6], acc[7]};
    #pragma unroll
    for (int q = 0; q < 4; ++q) {
        float4* pp = reinterpret_cast<float4*>(ob + (size_t)q * cstride);
        pp[0] = v0; pp[1] = v1;
    }
}

extern "C" void kernel_launch(void* const* d_in, const int* in_sizes, int n_in,
                              void* d_out, int out_size, void* d_ws, size_t ws_size,
                              hipStream_t stream) {
    const float* x      = (const float*)d_in[0];
    const float* scales = (const float*)d_in[1];
    float* out          = (float*)d_out;
    float* ws           = (float*)d_ws;   // taps 48KB + xpad 1.05MB

    prep_kernel<<<dim3(310), 256, 0, stream>>>(x, scales, ws);
    cwt_kernel<<<dim3(NBLOCK), 128, 0, stream>>>(scales, ws, out);
}

// Round 11
// 29.290 us; speedup vs baseline: 1.0705x; 1.0705x over previous
//
#include <hip/hip_runtime.h>

// CWT, truncated direct correlation, REAL PART ONLY (harness validates
// out_size = B*128*N float32 = real part of the complex64 reference).
//   y[n] = sum_{t=0}^{~T} x[n+t-8191] * g(t)*cos(2*pi*f*t),
//   g(t)=exp(-t^2/2sigma^2), sigma=6*scale/2pi, f=1/scale, T=ceil(5sigma)+1.
// ch%4 -> x row, ch%32 -> wavelet; 4|32 -> 32 unique channels, 4 copies.
// T<=307 -> y==0 exactly for n<7885; tiles 0..14 (512-wide) zero-filled.
//
// R10 lesson: LDS-vs-global, occupancy, tap count all ~null -> stall is the
// load->use round-trip per 16-tap group. R11: taps computed IN VALU inside
// the loop (wave-uniform, ~110 cyc/group) -- kills the tap loads AND fills
// the x-read latency window with useful work; single kernel (no prep).

#define NPIX   16384
#define NSCALE 32
#define NCH    4
#define ALPHA  5.0f
#define PI_F   3.14159265358979f
#define RPT    8
#define UBLK   512        // outputs per wave unit
#define WT0    15         // first working tile
#define NWT    17         // working tiles 15..31
#define NZT    15         // all-scale zero tiles 0..14
#define NBLOCK (NWT * NSCALE * NCH / 2)   // 1088 blocks (2 waves each)
#define NZUNIT (NZT * NSCALE * NCH)       // 1920 zero units
#define WINF   832        // staged window floats per wave (512 + 320)
#define LHALF  8191

__global__ __launch_bounds__(128) void cwt_kernel(
    const float* __restrict__ x,
    const float* __restrict__ scales,
    float* __restrict__ out)
{
    __shared__ float xs[2][WINF];   // 2 x 3.25 KB, one region per wave

    const int lane = threadIdx.x & 63;
    const int wid  = threadIdx.x >> 6;
    const int Bk   = blockIdx.x;
    const int W    = Bk * 2 + wid;            // global wave id 0..2175

    const size_t cstride = (size_t)NSCALE * NPIX;

    // ---- zero-fill duty: 1920 units x 512 floats x 4 copies ----
    if (W < NZUNIT) {
        const int zb = W / (NZT * NSCALE);
        const int rr = W % (NZT * NSCALE);
        const int zs = rr / NZT;
        const int zt = rr % NZT;
        float* zp = out + ((size_t)zb * (NSCALE * NCH) + zs) * NPIX
                        + zt * UBLK + lane * 8;
        const float4 z = {0.f, 0.f, 0.f, 0.f};
        #pragma unroll
        for (int q = 0; q < 4; ++q) {
            float4* pp = reinterpret_cast<float4*>(zp + (size_t)q * cstride);
            pp[0] = z; pp[1] = z;
        }
    }

    // ---- unit decode: pair p at stride 68 across blocks (no CU aliasing) ----
    const int p    = Bk / 68;                 // scale pair 0..15
    const int rr2  = Bk % 68;
    const int b    = rr2 / NWT;               // batch 0..3
    const int tile = WT0 + (rr2 % NWT);       // 15..31
    const int s    = wid ? (NSCALE - 1 - p) : p;

    const int n0 = tile * UBLK;
    const float scale = scales[s];
    const float sigma = 6.0f * scale / (2.0f * PI_F);
    int T = (int)ceilf(ALPHA * sigma) + 1;
    if (T > 307) T = 307;
    const int nG = (T + 15) >> 4;             // 1..20 groups of 16 taps

    // ---- stage x window: xs[wid][i] = x[n0 - 8191 + i], zero-padded ----
    {
        const float* xrow = x + ((size_t)b * NCH + (s & 3)) * NPIX;
        const int base = n0 - LHALF;
        #pragma unroll
        for (int k = 0; k < WINF / 64; ++k) {     // 13 iters
            const int i  = lane + k * 64;
            const int xi = base + i;
            xs[wid][i] = ((unsigned)xi < (unsigned)NPIX) ? xrow[xi] : 0.0f;
        }
    }
    // single-wave region: in-wave ds ordering via compiler lgkmcnt (no barrier)

    // ---- main loop: {4 ds_reads -> 16 VALU taps -> 128 FMAs} per group ----
    const float w2 = 2.0f * PI_F / scale;         // cos argument step
    const float c2 = -0.5f / (sigma * sigma);     // gaussian exponent coeff
    const float4* xs4 = reinterpret_cast<const float4*>(xs[wid]);
    const int wb = lane * 2;                      // float4 base for this lane

    float acc[RPT];
    #pragma unroll
    for (int j = 0; j < RPT; ++j) acc[j] = 0.f;

    float4 a0 = xs4[wb + 0], a1 = xs4[wb + 1], a2 = xs4[wb + 2];
    float4 a3 = xs4[wb + 3], a4 = xs4[wb + 4], a5 = xs4[wb + 5];
    float t0f = 0.0f;

    for (int g = 0; ; ) {
        // 16 wave-uniform taps in VALU (covers the ds_read latency)
        float tap[16];
        #pragma unroll
        for (int k = 0; k < 16; ++k) {
            const float tf = t0f + (float)k;
            tap[k] = __expf(c2 * tf * tf) * __cosf(w2 * tf);
        }

        const float e[24] = {a0.x,a0.y,a0.z,a0.w, a1.x,a1.y,a1.z,a1.w,
                             a2.x,a2.y,a2.z,a2.w, a3.x,a3.y,a3.z,a3.w,
                             a4.x,a4.y,a4.z,a4.w, a5.x,a5.y,a5.z,a5.w};
        #pragma unroll
        for (int k = 0; k < 16; ++k) {
            #pragma unroll
            for (int j = 0; j < RPT; ++j)
                acc[j] = fmaf(tap[k], e[k + j], acc[j]);
        }

        if (++g >= nG) break;

        // rotate window and issue next 4 reads EARLY (before next tap burst)
        a0 = a4; a1 = a5;
        const int jb = wb + g * 4;
        a2 = xs4[jb + 2]; a3 = xs4[jb + 3];
        a4 = xs4[jb + 4]; a5 = xs4[jb + 5];
        t0f += 16.0f;
    }

    // ---- store 4 channel copies (2 x float4 per copy) ----
    float* ob = out + ((size_t)b * (NSCALE * NCH) + s) * NPIX + n0 + lane * 8;
    const float4 v0 = {acc[0], acc[1], acc[2], acc[3]};
    const float4 v1 = {acc[4], acc[5], acc[6], acc[7]};
    #pragma unroll
    for (int q = 0; q < 4; ++q) {
        float4* pp = reinterpret_cast<float4*>(ob + (size_t)q * cstride);
        pp[0] = v0; pp[1] = v1;
    }
}

extern "C" void kernel_launch(void* const* d_in, const int* in_sizes, int n_in,
                              void* d_out, int out_size, void* d_ws, size_t ws_size,
                              hipStream_t stream) {
    const float* x      = (const float*)d_in[0];
    const float* scales = (const float*)d_in[1];
    float* out          = (float*)d_out;

    cwt_kernel<<<dim3(NBLOCK), 128, 0, stream>>>(x, scales, out);
}